// Round 9
// baseline (256.907 us; speedup 1.0000x reference)
//
#include <hip/hip_runtime.h>
#include <hip/hip_bf16.h>

typedef unsigned short u16;
typedef __attribute__((ext_vector_type(8))) short short8;
typedef __attribute__((ext_vector_type(4))) float f32x4;

#define MODEL 768
// 1/sqrt(128) * log2(e): exp(s/sqrt(128)) == exp2(s * SCALE2)
#define SCALE2 0.1275174137f

__device__ __forceinline__ float bf2f(u16 u) {
  unsigned int x = ((unsigned int)u) << 16;
  return __uint_as_float(x);
}
__device__ __forceinline__ u16 f2bf(float f) {
  unsigned int x = __float_as_uint(f);
  unsigned int r = (x + 0x7FFFu + ((x >> 16) & 1u)) >> 16;
  return (u16)r;
}
__device__ __forceinline__ void lds_ld16(const u16* g, u16* l) {
  __builtin_amdgcn_global_load_lds((const __attribute__((address_space(1))) void*)g,
                                   (__attribute__((address_space(3))) void*)l, 16, 0, 0);
}

// ---------------------------------------------------------------------------
// Kernel 1: x f32 -> bf16 (786432 float4 units)
// ---------------------------------------------------------------------------
__global__ __launch_bounds__(256) void r9_cvt_x(const float* __restrict__ x,
                                                u16* __restrict__ xb) {
  int i = blockIdx.x * 256 + threadIdx.x;
  float4 v = ((const float4*)x)[i];
  ushort4 o;
  o.x = f2bf(v.x); o.y = f2bf(v.y); o.z = f2bf(v.z); o.w = f2bf(v.w);
  ((ushort4*)xb)[i] = o;
}

// ---------------------------------------------------------------------------
// GEMM body: C[4096][768] = A_bf16 * W_f32^T, 128x128 tile, BK=32, 4 waves,
// 4x4 16x16x32 bf16 MFMA.  W converted f32->bf16 during staging.
// ---------------------------------------------------------------------------
template <int F32OUT>
__device__ __forceinline__ void gemm_body(const u16* __restrict__ A,
                                          const float* __restrict__ W,
                                          void* __restrict__ Cv) {
  __shared__ u16 As[128 * 32];
  __shared__ u16 Bs[128 * 32];
  const int tid = threadIdx.x;
  const int w = tid >> 6, l = tid & 63;
  const int lr = l & 15, lg = l >> 4;
  const int m0 = blockIdx.x * 128, n0 = blockIdx.y * 128;
  const int wr = (w >> 1) * 64, wc = (w & 1) * 64;
  const int sr = w * 32 + (l >> 2);
  const int sc = (l & 3) * 8;
  const int qrow = tid >> 1;
  const int qoff = (tid & 1) * 16;
  f32x4 acc[4][4] = {};
  for (int k0 = 0; k0 < 768; k0 += 32) {
    __syncthreads();
    lds_ld16(A + (size_t)(m0 + sr) * 768 + k0 + sc, As + (w * 2 + 0) * 512);
    lds_ld16(A + (size_t)(m0 + sr + 16) * 768 + k0 + sc, As + (w * 2 + 1) * 512);
    {
      const float* wp = W + (size_t)(n0 + qrow) * 768 + k0 + qoff;
      u16* bp = Bs + qrow * 32 + qoff;
#pragma unroll
      for (int q = 0; q < 4; q++) {
        float4 f = ((const float4*)wp)[q];
        ushort4 b;
        b.x = f2bf(f.x); b.y = f2bf(f.y); b.z = f2bf(f.z); b.w = f2bf(f.w);
        *(ushort4*)(bp + q * 4) = b;
      }
    }
    __syncthreads();
    short8 af[4], bfr[4];
#pragma unroll
    for (int mr = 0; mr < 4; mr++) af[mr] = *(const short8*)(As + (wr + mr * 16 + lr) * 32 + lg * 8);
#pragma unroll
    for (int nc = 0; nc < 4; nc++) bfr[nc] = *(const short8*)(Bs + (wc + nc * 16 + lr) * 32 + lg * 8);
#pragma unroll
    for (int mr = 0; mr < 4; mr++)
#pragma unroll
      for (int nc = 0; nc < 4; nc++)
        acc[mr][nc] = __builtin_amdgcn_mfma_f32_16x16x32_bf16(af[mr], bfr[nc], acc[mr][nc], 0, 0, 0);
  }
#pragma unroll
  for (int mr = 0; mr < 4; mr++)
#pragma unroll
    for (int nc = 0; nc < 4; nc++)
#pragma unroll
      for (int ri = 0; ri < 4; ri++) {
        int row = m0 + wr + mr * 16 + lg * 4 + ri;
        int col = n0 + wc + nc * 16 + lr;
        if (F32OUT) ((float*)Cv)[(size_t)row * 768 + col] = acc[mr][nc][ri];
        else        ((u16*)Cv)[(size_t)row * 768 + col] = f2bf(acc[mr][nc][ri]);
      }
}

__global__ __launch_bounds__(256) void r9_gemm_qkv(const u16* __restrict__ A,
                                                   const float* __restrict__ W0,
                                                   const float* __restrict__ W1,
                                                   const float* __restrict__ W2,
                                                   u16* __restrict__ C0,
                                                   u16* __restrict__ C1,
                                                   u16* __restrict__ C2) {
  const float* W = (blockIdx.z == 0) ? W0 : (blockIdx.z == 1) ? W1 : W2;
  u16* C = (blockIdx.z == 0) ? C0 : (blockIdx.z == 1) ? C1 : C2;
  gemm_body<0>(A, W, (void*)C);
}

__global__ __launch_bounds__(256) void r9_gemm_proj(const u16* __restrict__ A,
                                                    const float* __restrict__ W,
                                                    float* __restrict__ C) {
  gemm_body<1>(A, W, (void*)C);
}

// ---------------------------------------------------------------------------
// Kernel 3: fused RMS-norm + rotary (Q,K) + lambda-mix (V), in place.
// ---------------------------------------------------------------------------
__global__ __launch_bounds__(256) void r9_normrope(u16* __restrict__ qb,
                                                   u16* __restrict__ kb,
                                                   u16* __restrict__ vb,
                                                   const float* __restrict__ vres,
                                                   const float* __restrict__ lambp,
                                                   const int* __restrict__ pos) {
  const int wg = blockIdx.x * 4 + (threadIdx.x >> 6);
  const int l = threadIdx.x & 63;
  const int t = wg / 6;
  const int h = wg - t * 6;
  const size_t base = (size_t)t * MODEL + h * 128;
  const float EPS = 1.1920928955078125e-07f;

  float c = 1.0f, sn = 0.0f;
  if (l < 32) {
    float af = exp2f(-10.0f * (float)l * (1.0f / 31.0f));
    float th = (float)pos[t] * af;
    sincosf(th, &sn, &c);
  }
  {
    float a = bf2f(qb[base + l]), b = bf2f(qb[base + 64 + l]);
    float ss = a * a + b * b;
#pragma unroll
    for (int off = 32; off; off >>= 1) ss += __shfl_xor(ss, off);
    float r = rsqrtf(ss * (1.0f / 128.0f) + EPS);
    float an = a * r, bn = b * r;
    qb[base + l] = f2bf(an * c + bn * sn);
    qb[base + 64 + l] = f2bf(bn * c - an * sn);
  }
  {
    float a = bf2f(kb[base + l]), b = bf2f(kb[base + 64 + l]);
    float ss = a * a + b * b;
#pragma unroll
    for (int off = 32; off; off >>= 1) ss += __shfl_xor(ss, off);
    float r = rsqrtf(ss * (1.0f / 128.0f) + EPS);
    float an = a * r, bn = b * r;
    kb[base + l] = f2bf(an * c + bn * sn);
    kb[base + 64 + l] = f2bf(bn * c - an * sn);
  }
  {
    float lm = *lambp;
    float a = bf2f(vb[base + l]), b = bf2f(vb[base + 64 + l]);
    float ra = vres[base + l], rb = vres[base + 64 + l];
    vb[base + l] = f2bf((1.0f - lm) * a + lm * ra);
    vb[base + 64 + l] = f2bf((1.0f - lm) * b + lm * rb);
  }
}

// ---------------------------------------------------------------------------
// Kernel 4: causal flash attention, TLP-oriented.
// Block = 32 q-rows, 2 waves (128 thr), single-buffered LDS (~39 KB ->
// 4 blocks/CU co-resident; inter-block TLP hides staging & read latency).
// grid (128, 6), t = 127-bx (longest first).  Static-max softmax (Q,K rows
// RMS-normalized -> |s*scale| <= 11.4), rowsum via ones-MFMA.
// KVBLK=64; mask only on the final KV-iter of each tile.
// ---------------------------------------------------------------------------
__global__ __launch_bounds__(128) void r9_attn(const u16* __restrict__ Q,
                                               const u16* __restrict__ K,
                                               const u16* __restrict__ V,
                                               u16* __restrict__ Y) {
  const int h = blockIdx.y;
  const int t = 127 - blockIdx.x;          // q-tile (32 rows), longest first
  const int niter = (32 * t + 95) >> 6;    // KV tiles of 64 covering cols <= 32t+31
  const int tid = threadIdx.x;
  const int wv = tid >> 6, l = tid & 63;
  const int lr = l & 15, lg = l >> 4;

  __shared__ u16 Ks[64][128];     // 16 KB, col-block swizzle blk^(row&7)
  __shared__ u16 vt[128][72];     // 18 KB, V^T, r ^ ((d>>2&7)<<3)
  __shared__ u16 pls[2][16][72];  // 4.5 KB per-wave P

  const int c_ = tid & 31;        // V-stage dim group
  const int cc = c_ * 4;
  const int g = tid >> 5;         // 0..3 row-pair group
  const int vswz = (c_ & 7) << 3;

  short8 ones;
#pragma unroll
  for (int i = 0; i < 8; i++) ones[i] = (short)0x3F80;  // bf16 1.0

  const int qr = t * 32 + wv * 16;
  short8 qf[4];
  {
    const u16* qp = Q + (size_t)(qr + lr) * MODEL + h * 128 + lg * 8;
#pragma unroll
    for (int kc = 0; kc < 4; kc++) qf[kc] = *(const short8*)(qp + kc * 32);
  }
  f32x4 oacc[8] = {};
  f32x4 lacc = {};

  for (int kv = 0; kv < niter; kv++) {
    const int k0 = kv * 64;

    // ---- stage K tile (global_load_lds, source-swizzled) ----
    // Each gload_lds covers 4 rows (64 lanes x 16B = 1KB = 4*256B rows):
    // wave wv covers rows wv*32 .. wv*32+31 via 8 issues of 4 rows.
#pragma unroll
    for (int i = 0; i < 8; i++) {
      int rbase = wv * 32 + i * 4;
      int row = rbase + (l >> 4);
      int blk = (l & 15) ^ (row & 7);
      lds_ld16(K + (size_t)(k0 + row) * MODEL + h * 128 + blk * 8, &Ks[rbase][0]);
    }
    // ---- stage V^T (reg -> swizzled LDS) ----
#pragma unroll
    for (int it = 0; it < 8; it++) {
      int rloc = 2 * (g + 4 * it);
      ushort4 va = *(const ushort4*)(V + (size_t)(k0 + rloc) * MODEL + h * 128 + cc);
      ushort4 vb = *(const ushort4*)(V + (size_t)(k0 + rloc + 1) * MODEL + h * 128 + cc);
      int rs = rloc ^ vswz;
      u16 a0[4] = {va.x, va.y, va.z, va.w};
      u16 b0[4] = {vb.x, vb.y, vb.z, vb.w};
#pragma unroll
      for (int q = 0; q < 4; q++) {
        ushort2 t2; t2.x = a0[q]; t2.y = b0[q];
        *(ushort2*)&vt[cc + q][rs] = t2;
      }
    }
    __syncthreads();   // staging complete (drains vmcnt for gload_lds too)

    // ---- S = Q K^T ----
    f32x4 sac[4] = {};
    __builtin_amdgcn_s_setprio(1);
#pragma unroll
    for (int ct = 0; ct < 4; ct++) {
      const int r = ct * 16 + lr;
#pragma unroll
      for (int kc = 0; kc < 4; kc++) {
        short8 kf = *(const short8*)(&Ks[r][((4 * kc + lg) ^ (r & 7)) * 8]);
        sac[ct] = __builtin_amdgcn_mfma_f32_16x16x32_bf16(qf[kc], kf, sac[ct], 0, 0, 0);
      }
    }
    __builtin_amdgcn_s_setprio(0);

    // ---- static-max softmax: P = exp2(s*SCALE2) ----
    const bool maskit = (kv == niter - 1);
#pragma unroll
    for (int ri = 0; ri < 4; ri++) {
      const int row = qr + lg * 4 + ri;
#pragma unroll
      for (int ct = 0; ct < 4; ct++) {
        float xs = sac[ct][ri] * SCALE2;
        float p;
        if (maskit) {
          int col = k0 + ct * 16 + lr;
          p = (col <= row) ? exp2f(xs) : 0.0f;
        } else {
          p = exp2f(xs);
        }
        pls[wv][lg * 4 + ri][ct * 16 + lr] = f2bf(p);
      }
    }
    asm volatile("s_waitcnt lgkmcnt(0)" ::: "memory");  // wave-local P visible

    // ---- O += P V ;  l += P 1 ----
    __builtin_amdgcn_s_setprio(1);
#pragma unroll
    for (int kc2 = 0; kc2 < 2; kc2++) {
      short8 pf = *(const short8*)(&pls[wv][lr][kc2 * 32 + lg * 8]);
      lacc = __builtin_amdgcn_mfma_f32_16x16x32_bf16(pf, ones, lacc, 0, 0, 0);
#pragma unroll
      for (int dt = 0; dt < 8; dt++) {
        const int d = dt * 16 + lr;
        const int kb = (kc2 * 32 + lg * 8) ^ (((d >> 2) & 7) << 3);
        short8 vf = *(const short8*)(&vt[d][kb]);
        oacc[dt] = __builtin_amdgcn_mfma_f32_16x16x32_bf16(pf, vf, oacc[dt], 0, 0, 0);
      }
    }
    __builtin_amdgcn_s_setprio(0);
    __syncthreads();   // tile consumed; safe to re-stage next iter
  }

  // ---- write O ----
#pragma unroll
  for (int dt = 0; dt < 8; dt++)
#pragma unroll
    for (int ri = 0; ri < 4; ri++) {
      int row = qr + lg * 4 + ri;
      Y[(size_t)row * MODEL + h * 128 + dt * 16 + lr] = f2bf(oacc[dt][ri] / lacc[ri]);
    }
}

// ---------------------------------------------------------------------------
// d_out is FLOAT32: out0 = y@Wo^T [3145728 f32], out1 = v_residual [3145728].
// Workspace (u16 elems), 25.2 MB: xb@0 (aliased by yb), qb, kb, vb.
// ---------------------------------------------------------------------------
extern "C" void kernel_launch(void* const* d_in, const int* in_sizes, int n_in,
                              void* d_out, int out_size, void* d_ws, size_t ws_size,
                              hipStream_t stream) {
  const float* x = (const float*)d_in[0];
  const float* vres = (const float*)d_in[1];
  const float* Wq = (const float*)d_in[2];
  const float* Wk = (const float*)d_in[3];
  const float* Wv = (const float*)d_in[4];
  const float* Wo = (const float*)d_in[5];
  const float* lamb = (const float*)d_in[6];
  const int* pos = (const int*)d_in[7];
  float* out = (float*)d_out;

  u16* xb = (u16*)d_ws;
  u16* qb = xb + 3145728;
  u16* kb = qb + 3145728;
  u16* vb = kb + 3145728;
  u16* yb = xb;                   // alias: xb dead after QKV GEMMs
  float* out1 = out + 3145728;

  hipMemcpyAsync(out1, vres, 3145728 * sizeof(float), hipMemcpyDeviceToDevice, stream);

  r9_cvt_x<<<3072, 256, 0, stream>>>(x, xb);
  r9_gemm_qkv<<<dim3(32, 6, 3), 256, 0, stream>>>(xb, Wq, Wk, Wv, qb, kb, vb);
  r9_normrope<<<6144, 256, 0, stream>>>(qb, kb, vb, vres, lamb, pos);
  r9_attn<<<dim3(128, 6), 128, 0, stream>>>(qb, kb, vb, yb);
  r9_gemm_proj<<<dim3(32, 6), 256, 0, stream>>>(yb, Wo, out);
}

// Round 10
// 211.497 us; speedup vs baseline: 1.2147x; 1.2147x over previous
//
#include <hip/hip_runtime.h>
#include <hip/hip_bf16.h>

typedef unsigned short u16;
typedef __attribute__((ext_vector_type(8))) short short8;
typedef __attribute__((ext_vector_type(4))) float f32x4;

#define MODEL 768
// 1/sqrt(128) * log2(e): exp(s/sqrt(128)) == exp2(s * SCALE2)
#define SCALE2 0.1275174137f

__device__ __forceinline__ float bf2f(u16 u) {
  unsigned int x = ((unsigned int)u) << 16;
  return __uint_as_float(x);
}
__device__ __forceinline__ u16 f2bf(float f) {
  unsigned int x = __float_as_uint(f);
  unsigned int r = (x + 0x7FFFu + ((x >> 16) & 1u)) >> 16;
  return (u16)r;
}
__device__ __forceinline__ void lds_ld16(const u16* g, u16* l) {
  __builtin_amdgcn_global_load_lds((const __attribute__((address_space(1))) void*)g,
                                   (__attribute__((address_space(3))) void*)l, 16, 0, 0);
}

// ---------------------------------------------------------------------------
// Kernel 1: x f32 -> bf16 (786432 float4 units)
// ---------------------------------------------------------------------------
__global__ __launch_bounds__(256) void r10_cvt_x(const float* __restrict__ x,
                                                 u16* __restrict__ xb) {
  int i = blockIdx.x * 256 + threadIdx.x;
  float4 v = ((const float4*)x)[i];
  ushort4 o;
  o.x = f2bf(v.x); o.y = f2bf(v.y); o.z = f2bf(v.z); o.w = f2bf(v.w);
  ((ushort4*)xb)[i] = o;
}

// ---------------------------------------------------------------------------
// GEMM body: C[4096][768] = A_bf16 * W_f32^T, 128x128 tile, BK=32, 4 waves,
// 4x4 16x16x32 bf16 MFMA.  W converted f32->bf16 during staging.
// ---------------------------------------------------------------------------
template <int F32OUT>
__device__ __forceinline__ void gemm_body(const u16* __restrict__ A,
                                          const float* __restrict__ W,
                                          void* __restrict__ Cv) {
  __shared__ u16 As[128 * 32];
  __shared__ u16 Bs[128 * 32];
  const int tid = threadIdx.x;
  const int w = tid >> 6, l = tid & 63;
  const int lr = l & 15, lg = l >> 4;
  const int m0 = blockIdx.x * 128, n0 = blockIdx.y * 128;
  const int wr = (w >> 1) * 64, wc = (w & 1) * 64;
  const int sr = w * 32 + (l >> 2);
  const int sc = (l & 3) * 8;
  const int qrow = tid >> 1;
  const int qoff = (tid & 1) * 16;
  f32x4 acc[4][4] = {};
  for (int k0 = 0; k0 < 768; k0 += 32) {
    __syncthreads();
    lds_ld16(A + (size_t)(m0 + sr) * 768 + k0 + sc, As + (w * 2 + 0) * 512);
    lds_ld16(A + (size_t)(m0 + sr + 16) * 768 + k0 + sc, As + (w * 2 + 1) * 512);
    {
      const float* wp = W + (size_t)(n0 + qrow) * 768 + k0 + qoff;
      u16* bp = Bs + qrow * 32 + qoff;
#pragma unroll
      for (int q = 0; q < 4; q++) {
        float4 f = ((const float4*)wp)[q];
        ushort4 b;
        b.x = f2bf(f.x); b.y = f2bf(f.y); b.z = f2bf(f.z); b.w = f2bf(f.w);
        *(ushort4*)(bp + q * 4) = b;
      }
    }
    __syncthreads();
    short8 af[4], bfr[4];
#pragma unroll
    for (int mr = 0; mr < 4; mr++) af[mr] = *(const short8*)(As + (wr + mr * 16 + lr) * 32 + lg * 8);
#pragma unroll
    for (int nc = 0; nc < 4; nc++) bfr[nc] = *(const short8*)(Bs + (wc + nc * 16 + lr) * 32 + lg * 8);
#pragma unroll
    for (int mr = 0; mr < 4; mr++)
#pragma unroll
      for (int nc = 0; nc < 4; nc++)
        acc[mr][nc] = __builtin_amdgcn_mfma_f32_16x16x32_bf16(af[mr], bfr[nc], acc[mr][nc], 0, 0, 0);
  }
#pragma unroll
  for (int mr = 0; mr < 4; mr++)
#pragma unroll
    for (int nc = 0; nc < 4; nc++)
#pragma unroll
      for (int ri = 0; ri < 4; ri++) {
        int row = m0 + wr + mr * 16 + lg * 4 + ri;
        int col = n0 + wc + nc * 16 + lr;
        if (F32OUT) ((float*)Cv)[(size_t)row * 768 + col] = acc[mr][nc][ri];
        else        ((u16*)Cv)[(size_t)row * 768 + col] = f2bf(acc[mr][nc][ri]);
      }
}

__global__ __launch_bounds__(256) void r10_gemm_qkv(const u16* __restrict__ A,
                                                    const float* __restrict__ W0,
                                                    const float* __restrict__ W1,
                                                    const float* __restrict__ W2,
                                                    u16* __restrict__ C0,
                                                    u16* __restrict__ C1,
                                                    u16* __restrict__ C2) {
  const float* W = (blockIdx.z == 0) ? W0 : (blockIdx.z == 1) ? W1 : W2;
  u16* C = (blockIdx.z == 0) ? C0 : (blockIdx.z == 1) ? C1 : C2;
  gemm_body<0>(A, W, (void*)C);
}

__global__ __launch_bounds__(256) void r10_gemm_proj(const u16* __restrict__ A,
                                                     const float* __restrict__ W,
                                                     float* __restrict__ C) {
  gemm_body<1>(A, W, (void*)C);
}

// ---------------------------------------------------------------------------
// Kernel 3: fused RMS-norm + rotary (Q,K) + lambda-mix (V), in place.
// ---------------------------------------------------------------------------
__global__ __launch_bounds__(256) void r10_normrope(u16* __restrict__ qb,
                                                    u16* __restrict__ kb,
                                                    u16* __restrict__ vb,
                                                    const float* __restrict__ vres,
                                                    const float* __restrict__ lambp,
                                                    const int* __restrict__ pos) {
  const int wg = blockIdx.x * 4 + (threadIdx.x >> 6);
  const int l = threadIdx.x & 63;
  const int t = wg / 6;
  const int h = wg - t * 6;
  const size_t base = (size_t)t * MODEL + h * 128;
  const float EPS = 1.1920928955078125e-07f;

  float c = 1.0f, sn = 0.0f;
  if (l < 32) {
    float af = exp2f(-10.0f * (float)l * (1.0f / 31.0f));
    float th = (float)pos[t] * af;
    sincosf(th, &sn, &c);
  }
  {
    float a = bf2f(qb[base + l]), b = bf2f(qb[base + 64 + l]);
    float ss = a * a + b * b;
#pragma unroll
    for (int off = 32; off; off >>= 1) ss += __shfl_xor(ss, off);
    float r = rsqrtf(ss * (1.0f / 128.0f) + EPS);
    float an = a * r, bn = b * r;
    qb[base + l] = f2bf(an * c + bn * sn);
    qb[base + 64 + l] = f2bf(bn * c - an * sn);
  }
  {
    float a = bf2f(kb[base + l]), b = bf2f(kb[base + 64 + l]);
    float ss = a * a + b * b;
#pragma unroll
    for (int off = 32; off; off >>= 1) ss += __shfl_xor(ss, off);
    float r = rsqrtf(ss * (1.0f / 128.0f) + EPS);
    float an = a * r, bn = b * r;
    kb[base + l] = f2bf(an * c + bn * sn);
    kb[base + 64 + l] = f2bf(bn * c - an * sn);
  }
  {
    float lm = *lambp;
    float a = bf2f(vb[base + l]), b = bf2f(vb[base + 64 + l]);
    float ra = vres[base + l], rb = vres[base + 64 + l];
    vb[base + l] = f2bf((1.0f - lm) * a + lm * ra);
    vb[base + 64 + l] = f2bf((1.0f - lm) * b + lm * rb);
  }
}

// ---------------------------------------------------------------------------
// Kernel 4: causal flash attention, SPLIT-KV (static-max softmax makes KV
// chunks independent: partials just add).  Task = (head, q-tile of 32 rows,
// KV-chunk of 1024 cols = <=16 KVBLK iters).  1920 blocks, 2 waves each.
// Partials accumulated via hardware f32 atomics into accO/accL (zeroed).
// Tasks per head: qt 0..31 ->1 chunk, 32..63 ->2, 64..95 ->3, 96..127 ->4
// (chunk boundary 1024 never splits the diagonal: 32 | 1024).
// ---------------------------------------------------------------------------
__global__ __launch_bounds__(128) void r10_attn(const u16* __restrict__ Q,
                                                const u16* __restrict__ K,
                                                const u16* __restrict__ V,
                                                float* __restrict__ accO,
                                                float* __restrict__ accL) {
  // ---- decode task ----
  const int bx = blockIdx.x;         // 0..1919
  const int h = bx / 320;
  const int u = bx - h * 320;
  int qt, kc;
  if (u < 32)       { qt = u;                  kc = 0; }
  else if (u < 96)  { int v = u - 32;  qt = 32 + (v >> 1); kc = v & 1; }
  else if (u < 192) { int v = u - 96;  int q3 = v / 3; qt = 64 + q3; kc = v - 3 * q3; }
  else              { int v = u - 192; qt = 96 + (v >> 2); kc = v & 3; }
  const int rowmax = 32 * qt + 31;
  const int c0 = kc << 10;
  const bool islast = (c0 + 1024 > rowmax);
  const int cend = islast ? (rowmax + 1) : (c0 + 1024);
  const int niter = (cend - c0 + 63) >> 6;

  const int tid = threadIdx.x;
  const int wv = tid >> 6, l = tid & 63;
  const int lr = l & 15, lg = l >> 4;

  __shared__ u16 Ks[64][128];     // 16 KB, col-block swizzle blk^(row&7)
  __shared__ u16 vt[128][72];     // 18 KB, V^T, r ^ ((d>>2&7)<<3)
  __shared__ u16 pls[2][16][72];  // 4.5 KB per-wave P

  const int c_ = tid & 31;
  const int cc = c_ * 4;
  const int g = tid >> 5;
  const int vswz = (c_ & 7) << 3;

  short8 ones;
#pragma unroll
  for (int i = 0; i < 8; i++) ones[i] = (short)0x3F80;  // bf16 1.0

  const int qr = qt * 32 + wv * 16;
  short8 qf[4];
  {
    const u16* qp = Q + (size_t)(qr + lr) * MODEL + h * 128 + lg * 8;
#pragma unroll
    for (int kcf = 0; kcf < 4; kcf++) qf[kcf] = *(const short8*)(qp + kcf * 32);
  }
  f32x4 oacc[8] = {};
  f32x4 lacc = {};

  for (int kv = 0; kv < niter; kv++) {
    const int k0 = c0 + kv * 64;

    // ---- stage K tile (global_load_lds, source-swizzled); 4 rows/issue ----
#pragma unroll
    for (int i = 0; i < 8; i++) {
      int rbase = wv * 32 + i * 4;
      int row = rbase + (l >> 4);
      int blk = (l & 15) ^ (row & 7);
      lds_ld16(K + (size_t)(k0 + row) * MODEL + h * 128 + blk * 8, &Ks[rbase][0]);
    }
    // ---- stage V^T (reg -> swizzled LDS) ----
#pragma unroll
    for (int it = 0; it < 8; it++) {
      int rloc = 2 * (g + 4 * it);
      ushort4 va = *(const ushort4*)(V + (size_t)(k0 + rloc) * MODEL + h * 128 + cc);
      ushort4 vb = *(const ushort4*)(V + (size_t)(k0 + rloc + 1) * MODEL + h * 128 + cc);
      int rs = rloc ^ vswz;
      u16 a0[4] = {va.x, va.y, va.z, va.w};
      u16 b0[4] = {vb.x, vb.y, vb.z, vb.w};
#pragma unroll
      for (int q = 0; q < 4; q++) {
        ushort2 t2; t2.x = a0[q]; t2.y = b0[q];
        *(ushort2*)&vt[cc + q][rs] = t2;
      }
    }
    __syncthreads();   // staging complete (drains vmcnt for gload_lds too)

    // ---- S = Q K^T ----
    f32x4 sac[4] = {};
    __builtin_amdgcn_s_setprio(1);
#pragma unroll
    for (int ct = 0; ct < 4; ct++) {
      const int r = ct * 16 + lr;
#pragma unroll
      for (int kcf = 0; kcf < 4; kcf++) {
        short8 kf = *(const short8*)(&Ks[r][((4 * kcf + lg) ^ (r & 7)) * 8]);
        sac[ct] = __builtin_amdgcn_mfma_f32_16x16x32_bf16(qf[kcf], kf, sac[ct], 0, 0, 0);
      }
    }
    __builtin_amdgcn_s_setprio(0);

    // ---- static-max softmax: P = exp2(s*SCALE2) ----
    const bool maskit = islast && (kv == niter - 1);
#pragma unroll
    for (int ri = 0; ri < 4; ri++) {
      const int row = qr + lg * 4 + ri;
#pragma unroll
      for (int ct = 0; ct < 4; ct++) {
        float xs = sac[ct][ri] * SCALE2;
        float p;
        if (maskit) {
          int col = k0 + ct * 16 + lr;
          p = (col <= row) ? exp2f(xs) : 0.0f;
        } else {
          p = exp2f(xs);
        }
        pls[wv][lg * 4 + ri][ct * 16 + lr] = f2bf(p);
      }
    }
    asm volatile("s_waitcnt lgkmcnt(0)" ::: "memory");  // wave-local P visible

    // ---- O += P V ;  l += P 1 ----
    __builtin_amdgcn_s_setprio(1);
#pragma unroll
    for (int kc2 = 0; kc2 < 2; kc2++) {
      short8 pf = *(const short8*)(&pls[wv][lr][kc2 * 32 + lg * 8]);
      lacc = __builtin_amdgcn_mfma_f32_16x16x32_bf16(pf, ones, lacc, 0, 0, 0);
#pragma unroll
      for (int dt = 0; dt < 8; dt++) {
        const int d = dt * 16 + lr;
        const int kb = (kc2 * 32 + lg * 8) ^ (((d >> 2) & 7) << 3);
        short8 vf = *(const short8*)(&vt[d][kb]);
        oacc[dt] = __builtin_amdgcn_mfma_f32_16x16x32_bf16(pf, vf, oacc[dt], 0, 0, 0);
      }
    }
    __builtin_amdgcn_s_setprio(0);
    __syncthreads();   // tile consumed; safe to re-stage next iter
  }

  // ---- accumulate partials (f32 hardware atomics, <=4-way contention) ----
#pragma unroll
  for (int dt = 0; dt < 8; dt++)
#pragma unroll
    for (int ri = 0; ri < 4; ri++) {
      int row = qr + lg * 4 + ri;
      unsafeAtomicAdd(&accO[(size_t)row * 768 + h * 128 + dt * 16 + lr], oacc[dt][ri]);
    }
  if (lr == 0) {
#pragma unroll
    for (int ri = 0; ri < 4; ri++) {
      int row = qr + lg * 4 + ri;
      unsafeAtomicAdd(&accL[row * 6 + h], lacc[ri]);
    }
  }
}

// ---------------------------------------------------------------------------
// Kernel 5: finalize Y = accO / accL  (f32 -> bf16), 4 elems/thread.
// ---------------------------------------------------------------------------
__global__ __launch_bounds__(256) void r10_finalize(const float* __restrict__ accO,
                                                    const float* __restrict__ accL,
                                                    u16* __restrict__ Y) {
  int i = blockIdx.x * 256 + threadIdx.x;  // 786432 units of 4 elems
  f32x4 o = ((const f32x4*)accO)[i];
  int base = i * 4;
  int row = base / 768;
  int col = base - row * 768;
  float rl = 1.0f / accL[row * 6 + (col >> 7)];
  ushort4 y;
  y.x = f2bf(o[0] * rl); y.y = f2bf(o[1] * rl);
  y.z = f2bf(o[2] * rl); y.w = f2bf(o[3] * rl);
  ((ushort4*)Y)[i] = y;
}

// ---------------------------------------------------------------------------
// d_out FLOAT32: out0 = y@Wo^T [3145728 f32], out1 = v_residual [3145728].
// Workspace: xb@0 (6MB, aliased by yb), qb, kb, vb (18.9MB),
//            accO @ byte 25165824 (12.58MB f32), accL after (98KB). ~37.9MB.
// ---------------------------------------------------------------------------
extern "C" void kernel_launch(void* const* d_in, const int* in_sizes, int n_in,
                              void* d_out, int out_size, void* d_ws, size_t ws_size,
                              hipStream_t stream) {
  const float* x = (const float*)d_in[0];
  const float* vres = (const float*)d_in[1];
  const float* Wq = (const float*)d_in[2];
  const float* Wk = (const float*)d_in[3];
  const float* Wv = (const float*)d_in[4];
  const float* Wo = (const float*)d_in[5];
  const float* lamb = (const float*)d_in[6];
  const int* pos = (const int*)d_in[7];
  float* out = (float*)d_out;

  u16* xb = (u16*)d_ws;
  u16* qb = xb + 3145728;
  u16* kb = qb + 3145728;
  u16* vb = kb + 3145728;
  u16* yb = xb;                     // alias: xb dead after QKV GEMMs
  float* accO = (float*)((char*)d_ws + 25165824);
  float* accL = accO + 3145728;
  float* out1 = out + 3145728;

  hipMemcpyAsync(out1, vres, 3145728 * sizeof(float), hipMemcpyDeviceToDevice, stream);
  hipMemsetAsync(accO, 0, (3145728 + 24576) * sizeof(float), stream);

  r10_cvt_x<<<3072, 256, 0, stream>>>(x, xb);
  r10_gemm_qkv<<<dim3(32, 6, 3), 256, 0, stream>>>(xb, Wq, Wk, Wv, qb, kb, vb);
  r10_normrope<<<6144, 256, 0, stream>>>(qb, kb, vb, vres, lamb, pos);
  r10_attn<<<1920, 128, 0, stream>>>(qb, kb, vb, accO, accL);
  r10_finalize<<<3072, 256, 0, stream>>>(accO, accL, yb);
  r10_gemm_proj<<<dim3(32, 6), 256, 0, stream>>>(yb, Wo, out);
}

// Round 11
// 202.098 us; speedup vs baseline: 1.2712x; 1.0465x over previous
//
#include <hip/hip_runtime.h>
#include <hip/hip_bf16.h>

typedef unsigned short u16;
typedef __attribute__((ext_vector_type(8))) short short8;
typedef __attribute__((ext_vector_type(4))) float f32x4;

#define MODEL 768
// 1/sqrt(128) * log2(e): exp(s/sqrt(128)) == exp2(s * SCALE2)
#define SCALE2 0.1275174137f

__device__ __forceinline__ float bf2f(u16 u) {
  unsigned int x = ((unsigned int)u) << 16;
  return __uint_as_float(x);
}
__device__ __forceinline__ u16 f2bf(float f) {
  unsigned int x = __float_as_uint(f);
  unsigned int r = (x + 0x7FFFu + ((x >> 16) & 1u)) >> 16;
  return (u16)r;
}
__device__ __forceinline__ void lds_ld16(const u16* g, u16* l) {
  __builtin_amdgcn_global_load_lds((const __attribute__((address_space(1))) void*)g,
                                   (__attribute__((address_space(3))) void*)l, 16, 0, 0);
}

// ---------------------------------------------------------------------------
// Kernel 1: x f32 -> bf16 (786432 float4 units)
// ---------------------------------------------------------------------------
__global__ __launch_bounds__(256) void r11_cvt_x(const float* __restrict__ x,
                                                 u16* __restrict__ xb) {
  int i = blockIdx.x * 256 + threadIdx.x;
  float4 v = ((const float4*)x)[i];
  ushort4 o;
  o.x = f2bf(v.x); o.y = f2bf(v.y); o.z = f2bf(v.z); o.w = f2bf(v.w);
  ((ushort4*)xb)[i] = o;
}

// ---------------------------------------------------------------------------
// GEMM: C = A * W^T.  128x128 tile, BK=32, 4 waves, 4x4 16x16x32 bf16 MFMA.
// Variants: QKV (A bf16 via gload_lds, C bf16) and PROJ (A = f32 accO scaled
// by 1/accL during staging = fused attention-finalize, C f32 to d_out).
// ---------------------------------------------------------------------------
__global__ __launch_bounds__(256) void r11_gemm_qkv(const u16* __restrict__ A,
                                                    const float* __restrict__ W0,
                                                    const float* __restrict__ W1,
                                                    const float* __restrict__ W2,
                                                    u16* __restrict__ C0,
                                                    u16* __restrict__ C1,
                                                    u16* __restrict__ C2) {
  const float* W = (blockIdx.z == 0) ? W0 : (blockIdx.z == 1) ? W1 : W2;
  u16* C = (blockIdx.z == 0) ? C0 : (blockIdx.z == 1) ? C1 : C2;
  __shared__ u16 As[128 * 32];
  __shared__ u16 Bs[128 * 32];
  const int tid = threadIdx.x;
  const int w = tid >> 6, l = tid & 63;
  const int lr = l & 15, lg = l >> 4;
  const int m0 = blockIdx.x * 128, n0 = blockIdx.y * 128;
  const int wr = (w >> 1) * 64, wc = (w & 1) * 64;
  const int sr = w * 32 + (l >> 2);
  const int sc = (l & 3) * 8;
  const int qrow = tid >> 1;
  const int qoff = (tid & 1) * 16;
  f32x4 acc[4][4] = {};
  for (int k0 = 0; k0 < 768; k0 += 32) {
    __syncthreads();
    lds_ld16(A + (size_t)(m0 + sr) * 768 + k0 + sc, As + (w * 2 + 0) * 512);
    lds_ld16(A + (size_t)(m0 + sr + 16) * 768 + k0 + sc, As + (w * 2 + 1) * 512);
    {
      const float* wp = W + (size_t)(n0 + qrow) * 768 + k0 + qoff;
      u16* bp = Bs + qrow * 32 + qoff;
#pragma unroll
      for (int q = 0; q < 4; q++) {
        float4 f = ((const float4*)wp)[q];
        ushort4 b;
        b.x = f2bf(f.x); b.y = f2bf(f.y); b.z = f2bf(f.z); b.w = f2bf(f.w);
        *(ushort4*)(bp + q * 4) = b;
      }
    }
    __syncthreads();
    short8 af[4], bfr[4];
#pragma unroll
    for (int mr = 0; mr < 4; mr++) af[mr] = *(const short8*)(As + (wr + mr * 16 + lr) * 32 + lg * 8);
#pragma unroll
    for (int nc = 0; nc < 4; nc++) bfr[nc] = *(const short8*)(Bs + (wc + nc * 16 + lr) * 32 + lg * 8);
#pragma unroll
    for (int mr = 0; mr < 4; mr++)
#pragma unroll
      for (int nc = 0; nc < 4; nc++)
        acc[mr][nc] = __builtin_amdgcn_mfma_f32_16x16x32_bf16(af[mr], bfr[nc], acc[mr][nc], 0, 0, 0);
  }
#pragma unroll
  for (int mr = 0; mr < 4; mr++)
#pragma unroll
    for (int nc = 0; nc < 4; nc++)
#pragma unroll
      for (int ri = 0; ri < 4; ri++) {
        int row = m0 + wr + mr * 16 + lg * 4 + ri;
        int col = n0 + wc + nc * 16 + lr;
        C[(size_t)row * 768 + col] = f2bf(acc[mr][nc][ri]);
      }
}

// PROJ: A = accO/accL (fused finalize), output f32 straight to d_out.
__global__ __launch_bounds__(256) void r11_gemm_proj(const float* __restrict__ accO,
                                                     const float* __restrict__ accL,
                                                     const float* __restrict__ W,
                                                     float* __restrict__ C) {
  __shared__ u16 As[128 * 32];
  __shared__ u16 Bs[128 * 32];
  const int tid = threadIdx.x;
  const int w = tid >> 6, l = tid & 63;
  const int lr = l & 15, lg = l >> 4;
  const int m0 = blockIdx.x * 128, n0 = blockIdx.y * 128;
  const int wr = (w >> 1) * 64, wc = (w & 1) * 64;
  const int qrow = tid >> 1;
  const int qoff = (tid & 1) * 16;
  f32x4 acc[4][4] = {};
  for (int k0 = 0; k0 < 768; k0 += 32) {
    __syncthreads();
    {
      // A-staging with fused divide: Y[row][k] = accO[row][k] / accL[row, head(k)]
      const float* ap = accO + (size_t)(m0 + qrow) * 768 + k0 + qoff;
      float rl = 1.0f / accL[(m0 + qrow) * 6 + (k0 >> 7)];
      u16* dp = As + qrow * 32 + qoff;
#pragma unroll
      for (int q = 0; q < 4; q++) {
        float4 f = ((const float4*)ap)[q];
        ushort4 b;
        b.x = f2bf(f.x * rl); b.y = f2bf(f.y * rl);
        b.z = f2bf(f.z * rl); b.w = f2bf(f.w * rl);
        *(ushort4*)(dp + q * 4) = b;
      }
      const float* wp = W + (size_t)(n0 + qrow) * 768 + k0 + qoff;
      u16* bp = Bs + qrow * 32 + qoff;
#pragma unroll
      for (int q = 0; q < 4; q++) {
        float4 f = ((const float4*)wp)[q];
        ushort4 b;
        b.x = f2bf(f.x); b.y = f2bf(f.y); b.z = f2bf(f.z); b.w = f2bf(f.w);
        *(ushort4*)(bp + q * 4) = b;
      }
    }
    __syncthreads();
    short8 af[4], bfr[4];
#pragma unroll
    for (int mr = 0; mr < 4; mr++) af[mr] = *(const short8*)(As + (wr + mr * 16 + lr) * 32 + lg * 8);
#pragma unroll
    for (int nc = 0; nc < 4; nc++) bfr[nc] = *(const short8*)(Bs + (wc + nc * 16 + lr) * 32 + lg * 8);
#pragma unroll
    for (int mr = 0; mr < 4; mr++)
#pragma unroll
      for (int nc = 0; nc < 4; nc++)
        acc[mr][nc] = __builtin_amdgcn_mfma_f32_16x16x32_bf16(af[mr], bfr[nc], acc[mr][nc], 0, 0, 0);
  }
#pragma unroll
  for (int mr = 0; mr < 4; mr++)
#pragma unroll
    for (int nc = 0; nc < 4; nc++)
#pragma unroll
      for (int ri = 0; ri < 4; ri++) {
        int row = m0 + wr + mr * 16 + lg * 4 + ri;
        int col = n0 + wc + nc * 16 + lr;
        C[(size_t)row * 768 + col] = acc[mr][nc][ri];
      }
}

// ---------------------------------------------------------------------------
// Kernel 3: fused RMS-norm + rotary (Q,K) + lambda-mix (V), in place.
// ---------------------------------------------------------------------------
__global__ __launch_bounds__(256) void r11_normrope(u16* __restrict__ qb,
                                                    u16* __restrict__ kb,
                                                    u16* __restrict__ vb,
                                                    const float* __restrict__ vres,
                                                    const float* __restrict__ lambp,
                                                    const int* __restrict__ pos) {
  const int wg = blockIdx.x * 4 + (threadIdx.x >> 6);
  const int l = threadIdx.x & 63;
  const int t = wg / 6;
  const int h = wg - t * 6;
  const size_t base = (size_t)t * MODEL + h * 128;
  const float EPS = 1.1920928955078125e-07f;

  float c = 1.0f, sn = 0.0f;
  if (l < 32) {
    float af = exp2f(-10.0f * (float)l * (1.0f / 31.0f));
    float th = (float)pos[t] * af;
    sincosf(th, &sn, &c);
  }
  {
    float a = bf2f(qb[base + l]), b = bf2f(qb[base + 64 + l]);
    float ss = a * a + b * b;
#pragma unroll
    for (int off = 32; off; off >>= 1) ss += __shfl_xor(ss, off);
    float r = rsqrtf(ss * (1.0f / 128.0f) + EPS);
    float an = a * r, bn = b * r;
    qb[base + l] = f2bf(an * c + bn * sn);
    qb[base + 64 + l] = f2bf(bn * c - an * sn);
  }
  {
    float a = bf2f(kb[base + l]), b = bf2f(kb[base + 64 + l]);
    float ss = a * a + b * b;
#pragma unroll
    for (int off = 32; off; off >>= 1) ss += __shfl_xor(ss, off);
    float r = rsqrtf(ss * (1.0f / 128.0f) + EPS);
    float an = a * r, bn = b * r;
    kb[base + l] = f2bf(an * c + bn * sn);
    kb[base + 64 + l] = f2bf(bn * c - an * sn);
  }
  {
    float lm = *lambp;
    float a = bf2f(vb[base + l]), b = bf2f(vb[base + 64 + l]);
    float ra = vres[base + l], rb = vres[base + 64 + l];
    vb[base + l] = f2bf((1.0f - lm) * a + lm * ra);
    vb[base + 64 + l] = f2bf((1.0f - lm) * b + lm * rb);
  }
}

// ---------------------------------------------------------------------------
// Kernel 4: causal flash attention, SPLIT-KV, 4-wave blocks (64 q-rows).
// Task = (head, 64-row q-tile, 1024-col KV chunk): 160 tasks/head, 960
// blocks, decoded longest-first.  Each staged K/V tile feeds 4 waves
// (staging per wave halves vs r10); LDS 43 KB -> 3 blocks/CU = 12 waves/CU.
// Static-max softmax partials accumulate via f32 hardware atomics.
// ---------------------------------------------------------------------------
__global__ __launch_bounds__(256) void r11_attn(const u16* __restrict__ Q,
                                                const u16* __restrict__ K,
                                                const u16* __restrict__ V,
                                                float* __restrict__ accO,
                                                float* __restrict__ accL) {
  // ---- decode task (reversed u -> longest tasks first) ----
  const int bx = blockIdx.x;          // 0..959
  const int h = bx / 160;
  const int u = 159 - (bx - h * 160); // reversed
  int qt, kc;
  if (u < 16)      { qt = u;                      kc = 0; }
  else if (u < 48) { int v = u - 16; qt = 16 + (v >> 1); kc = v & 1; }
  else if (u < 96) { int v = u - 48; int q3 = v / 3; qt = 32 + q3; kc = v - 3 * q3; }
  else             { int v = u - 96; qt = 48 + (v >> 2); kc = v & 3; }
  const int rowmax = 64 * qt + 63;
  const int c0 = kc << 10;
  const bool islast = (c0 + 1024 > rowmax);
  const int cend = islast ? (rowmax + 1) : (c0 + 1024);
  const int niter = (cend - c0 + 63) >> 6;

  const int tid = threadIdx.x;
  const int wv = tid >> 6, l = tid & 63;
  const int lr = l & 15, lg = l >> 4;

  __shared__ u16 Ks[64][128];     // 16 KB, col-block swizzle blk^(row&7)
  __shared__ u16 vt[128][72];     // 18 KB, V^T, r ^ ((d>>2&7)<<3)
  __shared__ u16 pls[4][16][72];  // 9 KB per-wave P

  const int c_ = tid & 31;        // V-stage dim group (4 dims)
  const int cc = c_ * 4;
  const int g = tid >> 5;         // 0..7 row-pair group
  const int vswz = (c_ & 7) << 3;

  short8 ones;
#pragma unroll
  for (int i = 0; i < 8; i++) ones[i] = (short)0x3F80;  // bf16 1.0

  const int qr = qt * 64 + wv * 16;
  short8 qf[4];
  {
    const u16* qp = Q + (size_t)(qr + lr) * MODEL + h * 128 + lg * 8;
#pragma unroll
    for (int kcf = 0; kcf < 4; kcf++) qf[kcf] = *(const short8*)(qp + kcf * 32);
  }
  f32x4 oacc[8] = {};
  f32x4 lacc = {};

  for (int kv = 0; kv < niter; kv++) {
    const int k0 = c0 + kv * 64;

    // ---- stage K tile: each wave 16 rows via 4 issues of 4 rows ----
#pragma unroll
    for (int i = 0; i < 4; i++) {
      int rbase = wv * 16 + i * 4;
      int row = rbase + (l >> 4);
      int blk = (l & 15) ^ (row & 7);
      lds_ld16(K + (size_t)(k0 + row) * MODEL + h * 128 + blk * 8, &Ks[rbase][0]);
    }
    // ---- stage V^T (reg -> swizzled LDS), 4 row-pairs per thread ----
#pragma unroll
    for (int it = 0; it < 4; it++) {
      int rloc = 2 * (g + 8 * it);
      ushort4 va = *(const ushort4*)(V + (size_t)(k0 + rloc) * MODEL + h * 128 + cc);
      ushort4 vb = *(const ushort4*)(V + (size_t)(k0 + rloc + 1) * MODEL + h * 128 + cc);
      int rs = rloc ^ vswz;
      u16 a0[4] = {va.x, va.y, va.z, va.w};
      u16 b0[4] = {vb.x, vb.y, vb.z, vb.w};
#pragma unroll
      for (int q = 0; q < 4; q++) {
        ushort2 t2; t2.x = a0[q]; t2.y = b0[q];
        *(ushort2*)&vt[cc + q][rs] = t2;
      }
    }
    __syncthreads();   // staging complete (drains vmcnt for gload_lds too)

    // ---- S = Q K^T ----
    f32x4 sac[4] = {};
    __builtin_amdgcn_s_setprio(1);
#pragma unroll
    for (int ct = 0; ct < 4; ct++) {
      const int r = ct * 16 + lr;
#pragma unroll
      for (int kcf = 0; kcf < 4; kcf++) {
        short8 kf = *(const short8*)(&Ks[r][((4 * kcf + lg) ^ (r & 7)) * 8]);
        sac[ct] = __builtin_amdgcn_mfma_f32_16x16x32_bf16(qf[kcf], kf, sac[ct], 0, 0, 0);
      }
    }
    __builtin_amdgcn_s_setprio(0);

    // ---- static-max softmax: P = exp2(s*SCALE2) ----
    const bool maskit = islast && (kv == niter - 1);
#pragma unroll
    for (int ri = 0; ri < 4; ri++) {
      const int row = qr + lg * 4 + ri;
#pragma unroll
      for (int ct = 0; ct < 4; ct++) {
        float xs = sac[ct][ri] * SCALE2;
        float p;
        if (maskit) {
          int col = k0 + ct * 16 + lr;
          p = (col <= row) ? exp2f(xs) : 0.0f;
        } else {
          p = exp2f(xs);
        }
        pls[wv][lg * 4 + ri][ct * 16 + lr] = f2bf(p);
      }
    }
    asm volatile("s_waitcnt lgkmcnt(0)" ::: "memory");  // wave-local P visible

    // ---- O += P V ;  l += P 1 ----
    __builtin_amdgcn_s_setprio(1);
#pragma unroll
    for (int kc2 = 0; kc2 < 2; kc2++) {
      short8 pf = *(const short8*)(&pls[wv][lr][kc2 * 32 + lg * 8]);
      lacc = __builtin_amdgcn_mfma_f32_16x16x32_bf16(pf, ones, lacc, 0, 0, 0);
#pragma unroll
      for (int dt = 0; dt < 8; dt++) {
        const int d = dt * 16 + lr;
        const int kb = (kc2 * 32 + lg * 8) ^ (((d >> 2) & 7) << 3);
        short8 vf = *(const short8*)(&vt[d][kb]);
        oacc[dt] = __builtin_amdgcn_mfma_f32_16x16x32_bf16(pf, vf, oacc[dt], 0, 0, 0);
      }
    }
    __builtin_amdgcn_s_setprio(0);
    __syncthreads();   // tile consumed; safe to re-stage next iter
  }

  // ---- accumulate partials (f32 hardware atomics, <=4-way contention) ----
#pragma unroll
  for (int dt = 0; dt < 8; dt++)
#pragma unroll
    for (int ri = 0; ri < 4; ri++) {
      int row = qr + lg * 4 + ri;
      unsafeAtomicAdd(&accO[(size_t)row * 768 + h * 128 + dt * 16 + lr], oacc[dt][ri]);
    }
  if (lr == 0) {
#pragma unroll
    for (int ri = 0; ri < 4; ri++) {
      int row = qr + lg * 4 + ri;
      unsafeAtomicAdd(&accL[row * 6 + h], lacc[ri]);
    }
  }
}

// ---------------------------------------------------------------------------
// d_out FLOAT32: out0 = y@Wo^T [3145728 f32], out1 = v_residual [3145728].
// Workspace: xb@0 (6MB), qb, kb, vb (18.9MB),
//            accO @ byte 25165824 (12.58MB f32), accL after (98KB). ~37.9MB.
// ---------------------------------------------------------------------------
extern "C" void kernel_launch(void* const* d_in, const int* in_sizes, int n_in,
                              void* d_out, int out_size, void* d_ws, size_t ws_size,
                              hipStream_t stream) {
  const float* x = (const float*)d_in[0];
  const float* vres = (const float*)d_in[1];
  const float* Wq = (const float*)d_in[2];
  const float* Wk = (const float*)d_in[3];
  const float* Wv = (const float*)d_in[4];
  const float* Wo = (const float*)d_in[5];
  const float* lamb = (const float*)d_in[6];
  const int* pos = (const int*)d_in[7];
  float* out = (float*)d_out;

  u16* xb = (u16*)d_ws;
  u16* qb = xb + 3145728;
  u16* kb = qb + 3145728;
  u16* vb = kb + 3145728;
  float* accO = (float*)((char*)d_ws + 25165824);
  float* accL = accO + 3145728;
  float* out1 = out + 3145728;

  hipMemcpyAsync(out1, vres, 3145728 * sizeof(float), hipMemcpyDeviceToDevice, stream);
  hipMemsetAsync(accO, 0, (3145728 + 24576) * sizeof(float), stream);

  r11_cvt_x<<<3072, 256, 0, stream>>>(x, xb);
  r11_gemm_qkv<<<dim3(32, 6, 3), 256, 0, stream>>>(xb, Wq, Wk, Wv, qb, kb, vb);
  r11_normrope<<<6144, 256, 0, stream>>>(qb, kb, vb, vres, lamb, pos);
  r11_attn<<<960, 256, 0, stream>>>(qb, kb, vb, accO, accL);
  r11_gemm_proj<<<dim3(32, 6), 256, 0, stream>>>(accO, accL, Wo, out);
}

// Round 12
// 168.088 us; speedup vs baseline: 1.5284x; 1.2023x over previous
//
#include <hip/hip_runtime.h>
#include <hip/hip_bf16.h>

typedef unsigned short u16;
typedef __attribute__((ext_vector_type(8))) short short8;
typedef __attribute__((ext_vector_type(4))) float f32x4;
typedef __attribute__((ext_vector_type(16))) float f32x16;
typedef __attribute__((ext_vector_type(2))) unsigned int u32x2;

#define MODEL 768
// 1/sqrt(128) * log2(e): exp(s/sqrt(128)) == exp2(s * SCALE2)
#define SCALE2 0.1275174137f

__device__ __forceinline__ float bf2f(u16 u) {
  unsigned int x = ((unsigned int)u) << 16;
  return __uint_as_float(x);
}
__device__ __forceinline__ u16 f2bf(float f) {
  unsigned int x = __float_as_uint(f);
  unsigned int r = (x + 0x7FFFu + ((x >> 16) & 1u)) >> 16;
  return (u16)r;
}
__device__ __forceinline__ void lds_ld16(const u16* g, u16* l) {
  __builtin_amdgcn_global_load_lds((const __attribute__((address_space(1))) void*)g,
                                   (__attribute__((address_space(3))) void*)l, 16, 0, 0);
}
__device__ __forceinline__ unsigned int cvtpk_bf16(float lo, float hi_) {
  unsigned int r;
  asm("v_cvt_pk_bf16_f32 %0, %1, %2" : "=v"(r) : "v"(lo), "v"(hi_));
  return r;
}

// ---------------------------------------------------------------------------
// Kernel 1: x f32 -> bf16 (786432 float4 units)
// ---------------------------------------------------------------------------
__global__ __launch_bounds__(256) void r12_cvt_x(const float* __restrict__ x,
                                                 u16* __restrict__ xb) {
  int i = blockIdx.x * 256 + threadIdx.x;
  float4 v = ((const float4*)x)[i];
  ushort4 o;
  o.x = f2bf(v.x); o.y = f2bf(v.y); o.z = f2bf(v.z); o.w = f2bf(v.w);
  ((ushort4*)xb)[i] = o;
}

// ---------------------------------------------------------------------------
// GEMM QKV: C = A * W^T.  128x128 tile, BK=32, 4 waves, 16x16x32 bf16 MFMA.
// ---------------------------------------------------------------------------
__global__ __launch_bounds__(256) void r12_gemm_qkv(const u16* __restrict__ A,
                                                    const float* __restrict__ W0,
                                                    const float* __restrict__ W1,
                                                    const float* __restrict__ W2,
                                                    u16* __restrict__ C0,
                                                    u16* __restrict__ C1,
                                                    u16* __restrict__ C2) {
  const float* W = (blockIdx.z == 0) ? W0 : (blockIdx.z == 1) ? W1 : W2;
  u16* C = (blockIdx.z == 0) ? C0 : (blockIdx.z == 1) ? C1 : C2;
  __shared__ u16 As[128 * 32];
  __shared__ u16 Bs[128 * 32];
  const int tid = threadIdx.x;
  const int w = tid >> 6, l = tid & 63;
  const int lr = l & 15, lg = l >> 4;
  const int m0 = blockIdx.x * 128, n0 = blockIdx.y * 128;
  const int wr = (w >> 1) * 64, wc = (w & 1) * 64;
  const int sr = w * 32 + (l >> 2);
  const int sc = (l & 3) * 8;
  const int qrow = tid >> 1;
  const int qoff = (tid & 1) * 16;
  f32x4 acc[4][4] = {};
  for (int k0 = 0; k0 < 768; k0 += 32) {
    __syncthreads();
    lds_ld16(A + (size_t)(m0 + sr) * 768 + k0 + sc, As + (w * 2 + 0) * 512);
    lds_ld16(A + (size_t)(m0 + sr + 16) * 768 + k0 + sc, As + (w * 2 + 1) * 512);
    {
      const float* wp = W + (size_t)(n0 + qrow) * 768 + k0 + qoff;
      u16* bp = Bs + qrow * 32 + qoff;
#pragma unroll
      for (int q = 0; q < 4; q++) {
        float4 f = ((const float4*)wp)[q];
        ushort4 b;
        b.x = f2bf(f.x); b.y = f2bf(f.y); b.z = f2bf(f.z); b.w = f2bf(f.w);
        *(ushort4*)(bp + q * 4) = b;
      }
    }
    __syncthreads();
    short8 af[4], bfr[4];
#pragma unroll
    for (int mr = 0; mr < 4; mr++) af[mr] = *(const short8*)(As + (wr + mr * 16 + lr) * 32 + lg * 8);
#pragma unroll
    for (int nc = 0; nc < 4; nc++) bfr[nc] = *(const short8*)(Bs + (wc + nc * 16 + lr) * 32 + lg * 8);
#pragma unroll
    for (int mr = 0; mr < 4; mr++)
#pragma unroll
      for (int nc = 0; nc < 4; nc++)
        acc[mr][nc] = __builtin_amdgcn_mfma_f32_16x16x32_bf16(af[mr], bfr[nc], acc[mr][nc], 0, 0, 0);
  }
#pragma unroll
  for (int mr = 0; mr < 4; mr++)
#pragma unroll
    for (int nc = 0; nc < 4; nc++)
#pragma unroll
      for (int ri = 0; ri < 4; ri++) {
        int row = m0 + wr + mr * 16 + lg * 4 + ri;
        int col = n0 + wc + nc * 16 + lr;
        C[(size_t)row * 768 + col] = f2bf(acc[mr][nc][ri]);
      }
}

// PROJ: A = accO/accL (fused attention finalize), output f32 to d_out.
__global__ __launch_bounds__(256) void r12_gemm_proj(const float* __restrict__ accO,
                                                     const float* __restrict__ accL,
                                                     const float* __restrict__ W,
                                                     float* __restrict__ C) {
  __shared__ u16 As[128 * 32];
  __shared__ u16 Bs[128 * 32];
  const int tid = threadIdx.x;
  const int w = tid >> 6, l = tid & 63;
  const int lr = l & 15, lg = l >> 4;
  const int m0 = blockIdx.x * 128, n0 = blockIdx.y * 128;
  const int wr = (w >> 1) * 64, wc = (w & 1) * 64;
  const int qrow = tid >> 1;
  const int qoff = (tid & 1) * 16;
  f32x4 acc[4][4] = {};
  for (int k0 = 0; k0 < 768; k0 += 32) {
    __syncthreads();
    {
      const float* ap = accO + (size_t)(m0 + qrow) * 768 + k0 + qoff;
      float rl = 1.0f / accL[(m0 + qrow) * 6 + (k0 >> 7)];
      u16* dp = As + qrow * 32 + qoff;
#pragma unroll
      for (int q = 0; q < 4; q++) {
        float4 f = ((const float4*)ap)[q];
        ushort4 b;
        b.x = f2bf(f.x * rl); b.y = f2bf(f.y * rl);
        b.z = f2bf(f.z * rl); b.w = f2bf(f.w * rl);
        *(ushort4*)(dp + q * 4) = b;
      }
      const float* wp = W + (size_t)(n0 + qrow) * 768 + k0 + qoff;
      u16* bp = Bs + qrow * 32 + qoff;
#pragma unroll
      for (int q = 0; q < 4; q++) {
        float4 f = ((const float4*)wp)[q];
        ushort4 b;
        b.x = f2bf(f.x); b.y = f2bf(f.y); b.z = f2bf(f.z); b.w = f2bf(f.w);
        *(ushort4*)(bp + q * 4) = b;
      }
    }
    __syncthreads();
    short8 af[4], bfr[4];
#pragma unroll
    for (int mr = 0; mr < 4; mr++) af[mr] = *(const short8*)(As + (wr + mr * 16 + lr) * 32 + lg * 8);
#pragma unroll
    for (int nc = 0; nc < 4; nc++) bfr[nc] = *(const short8*)(Bs + (wc + nc * 16 + lr) * 32 + lg * 8);
#pragma unroll
    for (int mr = 0; mr < 4; mr++)
#pragma unroll
      for (int nc = 0; nc < 4; nc++)
        acc[mr][nc] = __builtin_amdgcn_mfma_f32_16x16x32_bf16(af[mr], bfr[nc], acc[mr][nc], 0, 0, 0);
  }
#pragma unroll
  for (int mr = 0; mr < 4; mr++)
#pragma unroll
    for (int nc = 0; nc < 4; nc++)
#pragma unroll
      for (int ri = 0; ri < 4; ri++) {
        int row = m0 + wr + mr * 16 + lg * 4 + ri;
        int col = n0 + wc + nc * 16 + lr;
        C[(size_t)row * 768 + col] = acc[mr][nc][ri];
      }
}

// ---------------------------------------------------------------------------
// Kernel 3: fused RMS-norm + rotary (Q,K) + lambda-mix (V), in place.
// ---------------------------------------------------------------------------
__global__ __launch_bounds__(256) void r12_normrope(u16* __restrict__ qb,
                                                    u16* __restrict__ kb,
                                                    u16* __restrict__ vb,
                                                    const float* __restrict__ vres,
                                                    const float* __restrict__ lambp,
                                                    const int* __restrict__ pos) {
  const int wg = blockIdx.x * 4 + (threadIdx.x >> 6);
  const int l = threadIdx.x & 63;
  const int t = wg / 6;
  const int h = wg - t * 6;
  const size_t base = (size_t)t * MODEL + h * 128;
  const float EPS = 1.1920928955078125e-07f;

  float c = 1.0f, sn = 0.0f;
  if (l < 32) {
    float af = exp2f(-10.0f * (float)l * (1.0f / 31.0f));
    float th = (float)pos[t] * af;
    sincosf(th, &sn, &c);
  }
  {
    float a = bf2f(qb[base + l]), b = bf2f(qb[base + 64 + l]);
    float ss = a * a + b * b;
#pragma unroll
    for (int off = 32; off; off >>= 1) ss += __shfl_xor(ss, off);
    float r = rsqrtf(ss * (1.0f / 128.0f) + EPS);
    float an = a * r, bn = b * r;
    qb[base + l] = f2bf(an * c + bn * sn);
    qb[base + 64 + l] = f2bf(bn * c - an * sn);
  }
  {
    float a = bf2f(kb[base + l]), b = bf2f(kb[base + 64 + l]);
    float ss = a * a + b * b;
#pragma unroll
    for (int off = 32; off; off >>= 1) ss += __shfl_xor(ss, off);
    float r = rsqrtf(ss * (1.0f / 128.0f) + EPS);
    float an = a * r, bn = b * r;
    kb[base + l] = f2bf(an * c + bn * sn);
    kb[base + 64 + l] = f2bf(bn * c - an * sn);
  }
  {
    float lm = *lambp;
    float a = bf2f(vb[base + l]), b = bf2f(vb[base + 64 + l]);
    float ra = vres[base + l], rb = vres[base + 64 + l];
    vb[base + l] = f2bf((1.0f - lm) * a + lm * ra);
    vb[base + 64 + l] = f2bf((1.0f - lm) * b + lm * rb);
  }
}

// ---------------------------------------------------------------------------
// Kernel 4: causal flash attention, SPLIT-KV, 32x32 MFMA, in-register P.
// 2 waves x 32 q-rows = 64-row tasks, chunk 1024 -> 960 blocks (r11 decode,
// longest-first).  Swapped QK^T (mfma(K,Q)) puts each lane's P on ONE q-row
// (col=lane&31): softmax = lane-local VALU; P->PV-A-frags via cvt_pk_bf16 +
// permlane32_swap (no P LDS, no fence).  LDS 34KB -> 4 blocks/CU.
// Partials accumulate via f32 hardware atomics (static-max softmax).
// ---------------------------------------------------------------------------
__global__ __launch_bounds__(128, 2) void r12_attn(const u16* __restrict__ Q,
                                                   const u16* __restrict__ K,
                                                   const u16* __restrict__ V,
                                                   float* __restrict__ accO,
                                                   float* __restrict__ accL) {
  // ---- decode task (reversed u -> longest first) ----
  const int bx = blockIdx.x;          // 0..959
  const int h = bx / 160;
  const int u = 159 - (bx - h * 160);
  int qt, kc;
  if (u < 16)      { qt = u;                      kc = 0; }
  else if (u < 48) { int v = u - 16; qt = 16 + (v >> 1); kc = v & 1; }
  else if (u < 96) { int v = u - 48; int q3 = v / 3; qt = 32 + q3; kc = v - 3 * q3; }
  else             { int v = u - 96; qt = 48 + (v >> 2); kc = v & 3; }
  const int rowmax = 64 * qt + 63;
  const int c0 = kc << 10;
  const bool islast = (c0 + 1024 > rowmax);
  const int cend = islast ? (rowmax + 1) : (c0 + 1024);
  const int niter = (cend - c0) >> 6;   // both multiples of 64

  const int tid = threadIdx.x;
  const int wv = tid >> 6, l = tid & 63;
  const int lq = l & 31;               // lane's q-col (QK^T) / d-col (PV)
  const int hi = l >> 5;

  __shared__ u16 Ks[64][128];     // 16 KB, col-block swizzle blk^(row&7)
  __shared__ u16 vt[128][72];     // 18 KB, V^T, kv-idx ^ ((d>>2&7)<<3)

  const int c_ = tid & 31, cc = c_ * 4, g = tid >> 5;  // V-stage coords
  const int vswz = (c_ & 7) << 3;

  const int qr = qt * 64 + wv * 32;
  const int qrow = qr + lq;

  // Q B-frags (wave-stationary): B[k][col=q]: lane holds q=lq, k=s*16+hi*8+j
  short8 qf[8];
  {
    const u16* qp = Q + (size_t)qrow * 768 + h * 128 + hi * 8;
#pragma unroll
    for (int s = 0; s < 8; s++) qf[s] = *(const short8*)(qp + s * 16);
  }
  f32x16 oacc[4] = {};
  float lsum = 0.0f;

  for (int kv = 0; kv < niter; kv++) {
    const int k0 = c0 + kv * 64;

    // ---- stage K tile (global_load_lds, source-swizzled); 4 rows/issue ----
#pragma unroll
    for (int i = 0; i < 8; i++) {
      int rbase = wv * 32 + i * 4;
      int row = rbase + (l >> 4);
      int blk = (l & 15) ^ (row & 7);
      lds_ld16(K + (size_t)(k0 + row) * 768 + h * 128 + blk * 8, &Ks[rbase][0]);
    }
    // ---- stage V^T (reg -> swizzled LDS), 8 row-pairs per thread ----
#pragma unroll
    for (int it = 0; it < 8; it++) {
      int rloc = 2 * (g + 4 * it);
      ushort4 va = *(const ushort4*)(V + (size_t)(k0 + rloc) * 768 + h * 128 + cc);
      ushort4 vb = *(const ushort4*)(V + (size_t)(k0 + rloc + 1) * 768 + h * 128 + cc);
      int rs = rloc ^ vswz;
      u16 a0[4] = {va.x, va.y, va.z, va.w};
      u16 b0[4] = {vb.x, vb.y, vb.z, vb.w};
#pragma unroll
      for (int q = 0; q < 4; q++) {
        ushort2 t2; t2.x = a0[q]; t2.y = b0[q];
        *(ushort2*)&vt[cc + q][rs] = t2;
      }
    }
    __syncthreads();   // staging complete (drains vmcnt for gload_lds too)

    // ---- S^T = K Q^T : 2 tiles of 32kv x 32q ----
    f32x16 sac0 = {}, sac1 = {};
    __builtin_amdgcn_s_setprio(1);
    {
      const int r0_ = lq, r1_ = 32 + lq;
#pragma unroll
      for (int s = 0; s < 8; s++) {
        short8 kf0 = *(const short8*)(&Ks[r0_][((s * 2 + hi) ^ (r0_ & 7)) * 8]);
        sac0 = __builtin_amdgcn_mfma_f32_32x32x16_bf16(kf0, qf[s], sac0, 0, 0, 0);
      }
#pragma unroll
      for (int s = 0; s < 8; s++) {
        short8 kf1 = *(const short8*)(&Ks[r1_][((s * 2 + hi) ^ (r1_ & 7)) * 8]);
        sac1 = __builtin_amdgcn_mfma_f32_32x32x16_bf16(kf1, qf[s], sac1, 0, 0, 0);
      }
    }
    __builtin_amdgcn_s_setprio(0);

    // ---- lane-local softmax: P = exp2(s*SCALE2); kv of reg r = crow(r,hi) ----
    float p[32];
    const bool maskit = islast && (kv == niter - 1);
    if (maskit) {
#pragma unroll
      for (int r = 0; r < 16; r++) {
        int kvg = k0 + (r & 3) + 8 * (r >> 2) + 4 * hi;
        p[r] = (kvg <= qrow) ? exp2f(sac0[r] * SCALE2) : 0.0f;
      }
#pragma unroll
      for (int r = 0; r < 16; r++) {
        int kvg = k0 + 32 + (r & 3) + 8 * (r >> 2) + 4 * hi;
        p[16 + r] = (kvg <= qrow) ? exp2f(sac1[r] * SCALE2) : 0.0f;
      }
    } else {
#pragma unroll
      for (int r = 0; r < 16; r++) p[r] = exp2f(sac0[r] * SCALE2);
#pragma unroll
      for (int r = 0; r < 16; r++) p[16 + r] = exp2f(sac1[r] * SCALE2);
    }
#pragma unroll
    for (int i = 0; i < 32; i++) lsum += p[i];

    // ---- pack P to PV A-frags: slice s covers kv 16s..16s+15 ----
    union { unsigned int w[4]; short8 v; } pa[4];
#pragma unroll
    for (int s = 0; s < 4; s++) {
      const int b = s * 8;
      unsigned int cA0 = cvtpk_bf16(p[b + 0], p[b + 1]);
      unsigned int cA1 = cvtpk_bf16(p[b + 2], p[b + 3]);
      unsigned int cB0 = cvtpk_bf16(p[b + 4], p[b + 5]);
      unsigned int cB1 = cvtpk_bf16(p[b + 6], p[b + 7]);
      u32x2 s0 = __builtin_amdgcn_permlane32_swap(cA0, cB0, false, false);
      u32x2 s1 = __builtin_amdgcn_permlane32_swap(cA1, cB1, false, false);
      pa[s].w[0] = s0[0]; pa[s].w[1] = s1[0]; pa[s].w[2] = s0[1]; pa[s].w[3] = s1[1];
    }

    // ---- O += P V : B-frag = V[kv=s*16+hi*8+j][d=dt*32+lq] from vt ----
    __builtin_amdgcn_s_setprio(1);
#pragma unroll
    for (int dt = 0; dt < 4; dt++) {
      const int d = dt * 32 + lq;
      const int dz = ((d >> 2) & 7) << 3;
#pragma unroll
      for (int s = 0; s < 4; s++) {
        short8 vf = *(const short8*)(&vt[d][(s * 16 + hi * 8) ^ dz]);
        oacc[dt] = __builtin_amdgcn_mfma_f32_32x32x16_bf16(pa[s].v, vf, oacc[dt], 0, 0, 0);
      }
    }
    __builtin_amdgcn_s_setprio(0);
    __syncthreads();   // tile consumed; safe to re-stage next iter
  }

  // ---- accumulate partials (f32 hardware atomics) ----
#pragma unroll
  for (int dt = 0; dt < 4; dt++) {
    const int d = dt * 32 + lq;
#pragma unroll
    for (int r = 0; r < 16; r++) {
      int qrw = qr + (r & 3) + 8 * (r >> 2) + 4 * hi;
      unsafeAtomicAdd(&accO[(size_t)qrw * 768 + h * 128 + d], oacc[dt][r]);
    }
  }
  // both hi-halves add their kv-partial rowsum for q-row qrow
  unsafeAtomicAdd(&accL[qrow * 6 + h], lsum);
}

// ---------------------------------------------------------------------------
// d_out FLOAT32: out0 = y@Wo^T [3145728 f32], out1 = v_residual [3145728].
// Workspace: xb@0 (6MB), qb, kb, vb (18.9MB),
//            accO @ byte 25165824 (12.58MB f32), accL after (98KB). ~37.9MB.
// ---------------------------------------------------------------------------
extern "C" void kernel_launch(void* const* d_in, const int* in_sizes, int n_in,
                              void* d_out, int out_size, void* d_ws, size_t ws_size,
                              hipStream_t stream) {
  const float* x = (const float*)d_in[0];
  const float* vres = (const float*)d_in[1];
  const float* Wq = (const float*)d_in[2];
  const float* Wk = (const float*)d_in[3];
  const float* Wv = (const float*)d_in[4];
  const float* Wo = (const float*)d_in[5];
  const float* lamb = (const float*)d_in[6];
  const int* pos = (const int*)d_in[7];
  float* out = (float*)d_out;

  u16* xb = (u16*)d_ws;
  u16* qb = xb + 3145728;
  u16* kb = qb + 3145728;
  u16* vb = kb + 3145728;
  float* accO = (float*)((char*)d_ws + 25165824);
  float* accL = accO + 3145728;
  float* out1 = out + 3145728;

  hipMemcpyAsync(out1, vres, 3145728 * sizeof(float), hipMemcpyDeviceToDevice, stream);
  hipMemsetAsync(accO, 0, (3145728 + 24576) * sizeof(float), stream);

  r12_cvt_x<<<3072, 256, 0, stream>>>(x, xb);
  r12_gemm_qkv<<<dim3(32, 6, 3), 256, 0, stream>>>(xb, Wq, Wk, Wv, qb, kb, vb);
  r12_normrope<<<6144, 256, 0, stream>>>(qb, kb, vb, vres, lamb, pos);
  r12_attn<<<960, 128, 0, stream>>>(qb, kb, vb, accO, accL);
  r12_gemm_proj<<<dim3(32, 6), 256, 0, stream>>>(accO, accL, Wo, out);
}